// Round 3
// baseline (1023.368 us; speedup 1.0000x reference)
//
#include <hip/hip_runtime.h>
#include <stdint.h>

#define SEQ   2048
#define NTOK  8192   // 4 * 2048

typedef unsigned short u16;
typedef __bf16 bf16x8 __attribute__((ext_vector_type(8)));
typedef float  f32x4  __attribute__((ext_vector_type(4)));

__device__ __forceinline__ float b2f(u16 b) {
    union { unsigned u; float f; } v; v.u = ((unsigned)b) << 16; return v.f;
}
__device__ __forceinline__ u16 f2b(float f) {
    union { float f; unsigned u; } v; v.f = f;
    unsigned r = (v.u + 0x7fffu + ((v.u >> 16) & 1u)) >> 16;
    return (u16)r;
}

__device__ __forceinline__ void gl_lds16(const void* g, void* l) {
    __builtin_amdgcn_global_load_lds(
        (const __attribute__((address_space(1))) void*)g,
        (__attribute__((address_space(3))) void*)l,
        16, 0, 0);
}

// ---------------------------------------------------------------------------
// fp32 -> bf16 conversion (weights), 4 elems/thread
// ---------------------------------------------------------------------------
__global__ __launch_bounds__(256)
void cvt_bf16(const float* __restrict__ s, u16* __restrict__ d, int n4)
{
    const int i = blockIdx.x * 256 + threadIdx.x;
    if (i < n4) {
        float4 v = ((const float4*)s)[i];
        ushort4 o;
        o.x = f2b(v.x); o.y = f2b(v.y); o.z = f2b(v.z); o.w = f2b(v.w);
        ((ushort4*)d)[i] = o;
    }
}

// ---------------------------------------------------------------------------
// GEMM: C[M][N] = A[M][K] * B[N][K]^T   (bf16 in, fp32 accum)
// 128x128 tile, BK=32, 4 waves, 4x4 MFMA 16x16x32 per wave (m97 structure).
// EPI 0: bf16 C[idx] = acc
// EPI 1: f32  C[idx] = acc + E_f32[idx]          (fused residual, fp32 out)
// EPI 2: bf16 C[idx] = silu(acc) * b2f(E[idx])   (fused SwiGLU; C==E ok)
// ---------------------------------------------------------------------------
template<int EPI>
__global__ __launch_bounds__(256)
void gemm_bt(const u16* __restrict__ A, const u16* __restrict__ B,
             void* __restrict__ C, const void* __restrict__ E,
             int M, int N, int K, int ldc, int coff)
{
    __shared__ __align__(16) u16 As[128 * 32];
    __shared__ __align__(16) u16 Bs[128 * 32];

    const int tid  = threadIdx.x;
    const int lane = tid & 63;
    const int wid  = tid >> 6;
    const int m0 = blockIdx.y * 128;
    const int n0 = blockIdx.x * 128;
    const int wm = (wid >> 1) * 64;
    const int wn = (wid & 1) * 64;
    const int am = lane & 15, grp = lane >> 4;

    f32x4 acc[4][4];
#pragma unroll
    for (int i = 0; i < 4; i++)
#pragma unroll
        for (int j = 0; j < 4; j++) acc[i][j] = (f32x4){0.f, 0.f, 0.f, 0.f};

    // staging: 16B chunk c -> row c>>2, k-chunk c&3. chunk0 = tid, chunk1 = tid+256
    const int r0  = tid >> 2;
    const int kc0 = (tid & 3) * 8;
    const u16* Ag0 = A + (size_t)(m0 + r0) * K + kc0;
    const u16* Ag1 = A + (size_t)(m0 + 64 + r0) * K + kc0;
    const u16* Bg0 = B + (size_t)(n0 + r0) * K + kc0;
    const u16* Bg1 = B + (size_t)(n0 + 64 + r0) * K + kc0;
    u16* Al0 = As + tid * 8;  u16* Al1 = As + (tid + 256) * 8;
    u16* Bl0 = Bs + tid * 8;  u16* Bl1 = Bs + (tid + 256) * 8;

    for (int kt = 0; kt < K; kt += 32) {
        __syncthreads();
        gl_lds16(Ag0 + kt, Al0);
        gl_lds16(Ag1 + kt, Al1);
        gl_lds16(Bg0 + kt, Bl0);
        gl_lds16(Bg1 + kt, Bl1);
        __syncthreads();

        bf16x8 af[4], bfv[4];
#pragma unroll
        for (int i = 0; i < 4; i++)
            af[i] = *(const bf16x8*)(&As[(wm + i * 16 + am) * 32 + grp * 8]);
#pragma unroll
        for (int j = 0; j < 4; j++)
            bfv[j] = *(const bf16x8*)(&Bs[(wn + j * 16 + am) * 32 + grp * 8]);
#pragma unroll
        for (int i = 0; i < 4; i++)
#pragma unroll
            for (int j = 0; j < 4; j++)
                acc[i][j] = __builtin_amdgcn_mfma_f32_16x16x32_bf16(
                    af[i], bfv[j], acc[i][j], 0, 0, 0);
    }

#pragma unroll
    for (int i = 0; i < 4; i++) {
#pragma unroll
        for (int r = 0; r < 4; r++) {
            const int row = m0 + wm + i * 16 + grp * 4 + r;
#pragma unroll
            for (int j = 0; j < 4; j++) {
                const int col = n0 + wn + j * 16 + am;
                const size_t idx = (size_t)row * ldc + coff + col;
                const float v = acc[i][j][r];
                if (EPI == 0) {
                    ((u16*)C)[idx] = f2b(v);
                } else if (EPI == 1) {
                    ((float*)C)[idx] = v + ((const float*)E)[idx];
                } else {
                    const float g = b2f(((const u16*)E)[idx]);
                    ((u16*)C)[idx] = f2b(v / (1.f + __expf(-v)) * g);
                }
            }
        }
    }
}

// ---------------------------------------------------------------------------
// RMSNorm: fp32 in, fp32 weight, bf16 out. One block/token, 256 thr x 4 elems
// ---------------------------------------------------------------------------
__global__ __launch_bounds__(256)
void rmsnorm_k(const float* __restrict__ xin, const float* __restrict__ w,
               u16* __restrict__ o)
{
    const int t = blockIdx.x;
    const int tid = threadIdx.x;
    float4 xv = ((const float4*)xin)[(size_t)t * 256 + tid];
    float ss = xv.x * xv.x + xv.y * xv.y + xv.z * xv.z + xv.w * xv.w;
#pragma unroll
    for (int off = 32; off > 0; off >>= 1) ss += __shfl_down(ss, off);
    __shared__ float red[4];
    const int lane = tid & 63, wv_ = tid >> 6;
    if (lane == 0) red[wv_] = ss;
    __syncthreads();
    const float tot = red[0] + red[1] + red[2] + red[3];
    const float inv = rsqrtf(tot * (1.f / 1024.f) + 1e-5f);
    float4 ww = ((const float4*)w)[tid];
    ushort4 ov;
    ov.x = f2b(xv.x * inv * ww.x);
    ov.y = f2b(xv.y * inv * ww.y);
    ov.z = f2b(xv.z * inv * ww.z);
    ov.w = f2b(xv.w * inv * ww.w);
    ((ushort4*)o)[(size_t)t * 256 + tid] = ov;
}

// ---------------------------------------------------------------------------
// RoPE tables (double precision, one-time) + apply (in place on q,k of qkv)
// ---------------------------------------------------------------------------
__global__ void rope_tab(float* __restrict__ cs, float* __restrict__ sn)
{
    const int s = blockIdx.x;      // position
    const int i = threadIdx.x;     // pair index 0..31
    const double inv = exp(-((double)(2 * i) / 64.0) * log(10000.0));
    const double ang = (double)s * inv;
    cs[s * 32 + i] = (float)cos(ang);
    sn[s * 32 + i] = (float)sin(ang);
}

__global__ __launch_bounds__(256)
void rope_apply(u16* __restrict__ qkv, const float* __restrict__ cs,
                const float* __restrict__ sn)
{
    const int t = blockIdx.x;
    const int s = t & (SEQ - 1);
    u16* row = qkv + (size_t)t * 3072;
    __shared__ float c_s[32], s_s[32];
    if (threadIdx.x < 32) {
        c_s[threadIdx.x] = cs[s * 32 + threadIdx.x];
        s_s[threadIdx.x] = sn[s * 32 + threadIdx.x];
    }
    __syncthreads();
#pragma unroll
    for (int rr = 0; rr < 2; rr++) {
        const int item = rr * 256 + threadIdx.x;   // 0..511 = head*32 + pair
        const int hh = item >> 5, i = item & 31;
        const int f = hh * 64 + 2 * i;
        const float c = c_s[i], sv = s_s[i];
        float xe = b2f(row[f]), xo = b2f(row[f + 1]);
        row[f]     = f2b(xe * c - xo * sv);
        row[f + 1] = f2b(xo * c + xe * sv);
        xe = b2f(row[1024 + f]); xo = b2f(row[1024 + f + 1]);
        row[1024 + f]     = f2b(xe * c - xo * sv);
        row[1024 + f + 1] = f2b(xo * c + xe * sv);
    }
}

// ---------------------------------------------------------------------------
// Flash attention (causal). Block = 64 q-rows of one (b,h); 4 waves x 16 rows.
// KV tiles of 32. QK^T and PV via mfma 16x16x32; P goes through LDS to
// convert C-layout -> A-layout (m120-verified).
// ---------------------------------------------------------------------------
__global__ __launch_bounds__(256)
void attn(const u16* __restrict__ qkv, u16* __restrict__ ao)
{
    __shared__ __align__(16) u16 Ks[32 * 64];
    __shared__ __align__(16) u16 Vt[64 * 40];     // [hd][key], padded stride 40
    __shared__ __align__(16) u16 Ps[4][16 * 32];  // per-wave P tile

    const int b = blockIdx.y >> 4, h = blockIdx.y & 15;
    const int qb = blockIdx.x * 64;
    const int tid = threadIdx.x, lane = tid & 63, wid = tid >> 6;
    const int am = lane & 15, grp = lane >> 4;
    const int qrow0 = qb + wid * 16;
    const size_t tok0 = (size_t)b * SEQ;
    const u16* base = qkv + tok0 * 3072 + h * 64;

    bf16x8 qf[2];
    {
        const u16* qp = base + (size_t)(qrow0 + am) * 3072 + grp * 8;
        qf[0] = *(const bf16x8*)(qp);
        qf[1] = *(const bf16x8*)(qp + 32);
    }

    f32x4 O[4];
    f32x4 m_i, l_i;
#pragma unroll
    for (int j = 0; j < 4; j++) O[j] = (f32x4){0.f, 0.f, 0.f, 0.f};
#pragma unroll
    for (int r = 0; r < 4; r++) { m_i[r] = -__builtin_inff(); l_i[r] = 0.f; }

    const int krow = tid >> 3, kc8 = (tid & 7) * 8;
    const float scale = 0.125f;   // 1/sqrt(64)

    for (int kt = 0; kt < qb + 64; kt += 32) {
        __syncthreads();
        const u16* kr = base + (size_t)(kt + krow) * 3072 + kc8;
        *(uint4*)(&Ks[krow * 64 + kc8]) = *(const uint4*)(kr + 1024);
        uint4 vv = *(const uint4*)(kr + 2048);
        const u16* pv = (const u16*)&vv;
#pragma unroll
        for (int j = 0; j < 8; j++) Vt[(kc8 + j) * 40 + krow] = pv[j];
        __syncthreads();

        f32x4 st[2];
#pragma unroll
        for (int kk = 0; kk < 2; kk++) {
            f32x4 s = (f32x4){0.f, 0.f, 0.f, 0.f};
            const u16* kb = &Ks[(kk * 16 + am) * 64 + grp * 8];
            bf16x8 k0 = *(const bf16x8*)(kb);
            bf16x8 k1 = *(const bf16x8*)(kb + 32);
            s = __builtin_amdgcn_mfma_f32_16x16x32_bf16(qf[0], k0, s, 0, 0, 0);
            s = __builtin_amdgcn_mfma_f32_16x16x32_bf16(qf[1], k1, s, 0, 0, 0);
#pragma unroll
            for (int r = 0; r < 4; r++) {
                const int qg = qrow0 + grp * 4 + r;
                const int kg = kt + kk * 16 + am;
                st[kk][r] = (kg <= qg) ? s[r] * scale : -1e30f;
            }
        }
        // row-reduce max over the 16 key lanes
        f32x4 mx;
#pragma unroll
        for (int r = 0; r < 4; r++) mx[r] = fmaxf(st[0][r], st[1][r]);
#pragma unroll
        for (int o = 1; o < 16; o <<= 1)
#pragma unroll
            for (int r = 0; r < 4; r++) mx[r] = fmaxf(mx[r], __shfl_xor(mx[r], o));

        f32x4 alpha, rs;
#pragma unroll
        for (int r = 0; r < 4; r++) {
            const float mnew = fmaxf(m_i[r], mx[r]);
            alpha[r] = __expf(m_i[r] - mnew);
            const float p0 = __expf(st[0][r] - mnew);
            const float p1 = __expf(st[1][r] - mnew);
            st[0][r] = p0; st[1][r] = p1;
            rs[r] = p0 + p1;
            m_i[r] = mnew;
        }
#pragma unroll
        for (int o = 1; o < 16; o <<= 1)
#pragma unroll
            for (int r = 0; r < 4; r++) rs[r] += __shfl_xor(rs[r], o);
#pragma unroll
        for (int r = 0; r < 4; r++) l_i[r] = l_i[r] * alpha[r] + rs[r];
#pragma unroll
        for (int j = 0; j < 4; j++)
#pragma unroll
            for (int r = 0; r < 4; r++) O[j][r] *= alpha[r];

        // P: C-layout -> LDS -> A-layout
        u16* prow = &Ps[wid][0];
#pragma unroll
        for (int r = 0; r < 4; r++) {
            prow[(grp * 4 + r) * 32 + am]      = f2b(st[0][r]);
            prow[(grp * 4 + r) * 32 + 16 + am] = f2b(st[1][r]);
        }
        asm volatile("s_waitcnt lgkmcnt(0)" ::: "memory");
        bf16x8 pf = *(const bf16x8*)(&prow[am * 32 + grp * 8]);
#pragma unroll
        for (int j = 0; j < 4; j++) {
            bf16x8 vf = *(const bf16x8*)(&Vt[(j * 16 + am) * 40 + grp * 8]);
            O[j] = __builtin_amdgcn_mfma_f32_16x16x32_bf16(pf, vf, O[j], 0, 0, 0);
        }
    }

    u16* aorow = ao + (tok0 + qrow0) * 1024 + h * 64;
#pragma unroll
    for (int r = 0; r < 4; r++) {
        const int q = grp * 4 + r;
        const float invl = 1.f / l_i[r];
#pragma unroll
        for (int j = 0; j < 4; j++)
            aorow[(size_t)q * 1024 + j * 16 + am] = f2b(O[j][r] * invl);
    }
}

// ---------------------------------------------------------------------------
extern "C" void kernel_launch(void* const* d_in, const int* in_sizes, int n_in,
                              void* d_out, int out_size, void* d_ws, size_t ws_size,
                              hipStream_t stream)
{
    (void)in_sizes; (void)n_in; (void)out_size; (void)ws_size;
    const float* x     = (const float*)d_in[0];
    const float* wq    = (const float*)d_in[1];
    const float* wk    = (const float*)d_in[2];
    const float* wv    = (const float*)d_in[3];
    const float* wo    = (const float*)d_in[4];
    const float* ln1   = (const float*)d_in[5];
    const float* ln2   = (const float*)d_in[6];
    const float* wup   = (const float*)d_in[7];
    const float* wgate = (const float*)d_in[8];
    const float* wdown = (const float*)d_in[9];
    float* out = (float*)d_out;
    char* ws = (char*)d_ws;
    const size_t MB = 1024 * 1024;

    // region R1 (0..16MB):   xn1 -> ao -> xn2   (sequential lifetimes)
    // region R2 (16..80MB):  qkv bf16 (48MB) -> hbuf bf16 (64MB)
    // region R3 (80..112MB): x1 fp32 residual (32MB)
    // region R4 (112..144MB): bf16 weights
    // tables at 144MB (512KB)
    u16*   xn   = (u16*)(ws);
    u16*   ao   = (u16*)(ws);
    u16*   qkv  = (u16*)(ws + 16 * MB);
    u16*   hbuf = (u16*)(ws + 16 * MB);
    float* x1   = (float*)(ws + 80 * MB);
    u16*   bwq  = (u16*)(ws + 112 * MB);             // 2MB
    u16*   bwk  = (u16*)(ws + 114 * MB);             // 2MB
    u16*   bwv  = (u16*)(ws + 116 * MB);             // 2MB
    u16*   bwo  = (u16*)(ws + 118 * MB);             // 2MB
    u16*   bwup = (u16*)(ws + 120 * MB);             // 8MB
    u16*   bwgt = (u16*)(ws + 128 * MB);             // 8MB
    u16*   bwdn = (u16*)(ws + 136 * MB);             // 8MB
    float* cst  = (float*)(ws + 144 * MB);
    float* snt  = (float*)(ws + 144 * MB + 262144);

    const int n4_1m = (1024 * 1024) / 4;             // 1M-elem weights
    const int n4_4m = (4096 * 1024) / 4;             // 4M-elem weights
    cvt_bf16<<<(n4_1m + 255) / 256, 256, 0, stream>>>(wq,    bwq,  n4_1m);
    cvt_bf16<<<(n4_1m + 255) / 256, 256, 0, stream>>>(wk,    bwk,  n4_1m);
    cvt_bf16<<<(n4_1m + 255) / 256, 256, 0, stream>>>(wv,    bwv,  n4_1m);
    cvt_bf16<<<(n4_1m + 255) / 256, 256, 0, stream>>>(wo,    bwo,  n4_1m);
    cvt_bf16<<<(n4_4m + 255) / 256, 256, 0, stream>>>(wup,   bwup, n4_4m);
    cvt_bf16<<<(n4_4m + 255) / 256, 256, 0, stream>>>(wgate, bwgt, n4_4m);
    cvt_bf16<<<(n4_4m + 255) / 256, 256, 0, stream>>>(wdown, bwdn, n4_4m);

    rope_tab<<<SEQ, 32, 0, stream>>>(cst, snt);
    rmsnorm_k<<<NTOK, 256, 0, stream>>>(x, ln1, xn);
    gemm_bt<0><<<dim3(8, 64), 256, 0, stream>>>(xn, bwq, qkv, nullptr, NTOK, 1024, 1024, 3072, 0);
    gemm_bt<0><<<dim3(8, 64), 256, 0, stream>>>(xn, bwk, qkv, nullptr, NTOK, 1024, 1024, 3072, 1024);
    gemm_bt<0><<<dim3(8, 64), 256, 0, stream>>>(xn, bwv, qkv, nullptr, NTOK, 1024, 1024, 3072, 2048);
    rope_apply<<<NTOK, 256, 0, stream>>>(qkv, cst, snt);
    attn<<<dim3(32, 64), 256, 0, stream>>>(qkv, ao);
    gemm_bt<1><<<dim3(8, 64), 256, 0, stream>>>(ao, bwo, x1, x, NTOK, 1024, 1024, 1024, 0);
    rmsnorm_k<<<NTOK, 256, 0, stream>>>(x1, ln2, xn);
    gemm_bt<0><<<dim3(32, 64), 256, 0, stream>>>(xn, bwgt, hbuf, nullptr, NTOK, 4096, 1024, 4096, 0);
    gemm_bt<2><<<dim3(32, 64), 256, 0, stream>>>(xn, bwup, hbuf, hbuf, NTOK, 4096, 1024, 4096, 0);
    gemm_bt<1><<<dim3(8, 64), 256, 0, stream>>>(hbuf, bwdn, out, x1, NTOK, 1024, 4096, 1024, 0);
}

// Round 4
// 740.074 us; speedup vs baseline: 1.3828x; 1.3828x over previous
//
#include <hip/hip_runtime.h>
#include <stdint.h>

#define SEQ   2048
#define NTOK  8192   // 4 * 2048

typedef unsigned short u16;
typedef __bf16 bf16x8 __attribute__((ext_vector_type(8)));
typedef float  f32x4  __attribute__((ext_vector_type(4)));

__device__ __forceinline__ float b2f(u16 b) {
    union { unsigned u; float f; } v; v.u = ((unsigned)b) << 16; return v.f;
}
__device__ __forceinline__ u16 f2b(float f) {
    union { float f; unsigned u; } v; v.f = f;
    unsigned r = (v.u + 0x7fffu + ((v.u >> 16) & 1u)) >> 16;
    return (u16)r;
}

__device__ __forceinline__ void gl_lds16(const void* g, void* l) {
    __builtin_amdgcn_global_load_lds(
        (const __attribute__((address_space(1))) void*)g,
        (__attribute__((address_space(3))) void*)l,
        16, 0, 0);
}

// ---------------------------------------------------------------------------
// fp32 -> bf16 conversion (weights), 4 elems/thread
// ---------------------------------------------------------------------------
__global__ __launch_bounds__(256)
void cvt_bf16(const float* __restrict__ s, u16* __restrict__ d, int n4)
{
    const int i = blockIdx.x * 256 + threadIdx.x;
    if (i < n4) {
        float4 v = ((const float4*)s)[i];
        ushort4 o;
        o.x = f2b(v.x); o.y = f2b(v.y); o.z = f2b(v.z); o.w = f2b(v.w);
        ((ushort4*)d)[i] = o;
    }
}

// ---------------------------------------------------------------------------
// GEMM: C[M][N] = A[M][K] * B[N][K]^T   (bf16 in, fp32 accum)
// 128x128 tile, BK=32, 4 waves, 4x4 MFMA 16x16x32 per wave (m97 structure).
// EPI 0: bf16 C[idx] = acc
// EPI 1: f32  C[idx] = acc + E_f32[idx]          (fused residual, fp32 out)
// EPI 2: bf16 C[idx] = silu(acc) * b2f(E[idx])   (fused SwiGLU; C==E ok)
// ---------------------------------------------------------------------------
template<int EPI>
__global__ __launch_bounds__(256)
void gemm_bt(const u16* __restrict__ A, const u16* __restrict__ B,
             void* __restrict__ C, const void* __restrict__ E,
             int M, int N, int K, int ldc, int coff)
{
    __shared__ __align__(16) u16 As[128 * 32];
    __shared__ __align__(16) u16 Bs[128 * 32];

    const int tid  = threadIdx.x;
    const int lane = tid & 63;
    const int wid  = tid >> 6;
    const int m0 = blockIdx.y * 128;
    const int n0 = blockIdx.x * 128;
    const int wm = (wid >> 1) * 64;
    const int wn = (wid & 1) * 64;
    const int am = lane & 15, grp = lane >> 4;

    f32x4 acc[4][4];
#pragma unroll
    for (int i = 0; i < 4; i++)
#pragma unroll
        for (int j = 0; j < 4; j++) acc[i][j] = (f32x4){0.f, 0.f, 0.f, 0.f};

    const int r0  = tid >> 2;
    const int kc0 = (tid & 3) * 8;
    const u16* Ag0 = A + (size_t)(m0 + r0) * K + kc0;
    const u16* Ag1 = A + (size_t)(m0 + 64 + r0) * K + kc0;
    const u16* Bg0 = B + (size_t)(n0 + r0) * K + kc0;
    const u16* Bg1 = B + (size_t)(n0 + 64 + r0) * K + kc0;
    u16* Al0 = As + tid * 8;  u16* Al1 = As + (tid + 256) * 8;
    u16* Bl0 = Bs + tid * 8;  u16* Bl1 = Bs + (tid + 256) * 8;

    for (int kt = 0; kt < K; kt += 32) {
        __syncthreads();
        gl_lds16(Ag0 + kt, Al0);
        gl_lds16(Ag1 + kt, Al1);
        gl_lds16(Bg0 + kt, Bl0);
        gl_lds16(Bg1 + kt, Bl1);
        __syncthreads();

        bf16x8 af[4], bfv[4];
#pragma unroll
        for (int i = 0; i < 4; i++)
            af[i] = *(const bf16x8*)(&As[(wm + i * 16 + am) * 32 + grp * 8]);
#pragma unroll
        for (int j = 0; j < 4; j++)
            bfv[j] = *(const bf16x8*)(&Bs[(wn + j * 16 + am) * 32 + grp * 8]);
#pragma unroll
        for (int i = 0; i < 4; i++)
#pragma unroll
            for (int j = 0; j < 4; j++)
                acc[i][j] = __builtin_amdgcn_mfma_f32_16x16x32_bf16(
                    af[i], bfv[j], acc[i][j], 0, 0, 0);
    }

#pragma unroll
    for (int i = 0; i < 4; i++) {
#pragma unroll
        for (int r = 0; r < 4; r++) {
            const int row = m0 + wm + i * 16 + grp * 4 + r;
#pragma unroll
            for (int j = 0; j < 4; j++) {
                const int col = n0 + wn + j * 16 + am;
                const size_t idx = (size_t)row * ldc + coff + col;
                const float v = acc[i][j][r];
                if (EPI == 0) {
                    ((u16*)C)[idx] = f2b(v);
                } else if (EPI == 1) {
                    ((float*)C)[idx] = v + ((const float*)E)[idx];
                } else {
                    const float g = b2f(((const u16*)E)[idx]);
                    ((u16*)C)[idx] = f2b(v / (1.f + __expf(-v)) * g);
                }
            }
        }
    }
}

// ---------------------------------------------------------------------------
// RMSNorm: fp32 in, fp32 weight, bf16 out. One block/token, 256 thr x 4 elems
// ---------------------------------------------------------------------------
__global__ __launch_bounds__(256)
void rmsnorm_k(const float* __restrict__ xin, const float* __restrict__ w,
               u16* __restrict__ o)
{
    const int t = blockIdx.x;
    const int tid = threadIdx.x;
    float4 xv = ((const float4*)xin)[(size_t)t * 256 + tid];
    float ss = xv.x * xv.x + xv.y * xv.y + xv.z * xv.z + xv.w * xv.w;
#pragma unroll
    for (int off = 32; off > 0; off >>= 1) ss += __shfl_down(ss, off);
    __shared__ float red[4];
    const int lane = tid & 63, wv_ = tid >> 6;
    if (lane == 0) red[wv_] = ss;
    __syncthreads();
    const float tot = red[0] + red[1] + red[2] + red[3];
    const float inv = rsqrtf(tot * (1.f / 1024.f) + 1e-5f);
    float4 ww = ((const float4*)w)[tid];
    ushort4 ov;
    ov.x = f2b(xv.x * inv * ww.x);
    ov.y = f2b(xv.y * inv * ww.y);
    ov.z = f2b(xv.z * inv * ww.z);
    ov.w = f2b(xv.w * inv * ww.w);
    ((ushort4*)o)[(size_t)t * 256 + tid] = ov;
}

// ---------------------------------------------------------------------------
// RoPE tables + apply. Q additionally scaled by 0.125 (1/sqrt(64), exact).
// ---------------------------------------------------------------------------
__global__ void rope_tab(float* __restrict__ cs, float* __restrict__ sn)
{
    const int s = blockIdx.x;
    const int i = threadIdx.x;
    const double inv = exp(-((double)(2 * i) / 64.0) * log(10000.0));
    const double ang = (double)s * inv;
    cs[s * 32 + i] = (float)cos(ang);
    sn[s * 32 + i] = (float)sin(ang);
}

__global__ __launch_bounds__(256)
void rope_apply(u16* __restrict__ qkv, const float* __restrict__ cs,
                const float* __restrict__ sn)
{
    const int t = blockIdx.x;
    const int s = t & (SEQ - 1);
    u16* row = qkv + (size_t)t * 3072;
    __shared__ float c_s[32], s_s[32];
    if (threadIdx.x < 32) {
        c_s[threadIdx.x] = cs[s * 32 + threadIdx.x];
        s_s[threadIdx.x] = sn[s * 32 + threadIdx.x];
    }
    __syncthreads();
#pragma unroll
    for (int rr = 0; rr < 2; rr++) {
        const int item = rr * 256 + threadIdx.x;
        const int hh = item >> 5, i = item & 31;
        const int f = hh * 64 + 2 * i;
        const float c = c_s[i], sv = s_s[i];
        float xe = b2f(row[f]), xo = b2f(row[f + 1]);
        row[f]     = f2b((xe * c - xo * sv) * 0.125f);   // Q: fold softmax scale
        row[f + 1] = f2b((xo * c + xe * sv) * 0.125f);
        xe = b2f(row[1024 + f]); xo = b2f(row[1024 + f + 1]);
        row[1024 + f]     = f2b(xe * c - xo * sv);       // K: unscaled
        row[1024 + f + 1] = f2b(xo * c + xe * sv);
    }
}

// ---------------------------------------------------------------------------
// Flash attention (causal), balanced. Block = 2 q-tiles (qx and 31-qx) of 64
// rows each; 4 waves x 16 q-rows. KV tiles of 64 keys.
// K staged [64][72] u16 (pad kills stride==0 mod 32 conflicts).
// V staged transposed as u32 key-pairs: Vt32[d][kp], stride 33 dwords.
// Row-sum l via ones-column MFMA (no shuffle reduce).
// ---------------------------------------------------------------------------
__global__ __launch_bounds__(256)
void attn(const u16* __restrict__ qkv, u16* __restrict__ ao)
{
    __shared__ __align__(16) u16  Ks[64 * 72];       // 9216 B
    __shared__ __align__(16) uint Vt32[64 * 33];     // 8448 B
    __shared__ __align__(16) u16  Ps[4][16 * 72];    // 9216 B

    const int bh = blockIdx.x;                // fast dim: same bh -> same XCD set
    const int qx = blockIdx.y;                // 0..15
    const int b = bh >> 4, h = bh & 15;
    const int tid = threadIdx.x, lane = tid & 63, wid = tid >> 6;
    const int am = lane & 15, grp = lane >> 4;
    const size_t tok0 = (size_t)b * SEQ;
    const u16* qbase = qkv + tok0 * 3072 + h * 64;
    const u16* kbase = qbase + 1024;
    const u16* vbase = qbase + 2048;

    // ones B-fragment (bf16 1.0 x8)
    union { uint4 u; bf16x8 b; } onesu;
    onesu.u = (uint4){0x3f803f80u, 0x3f803f80u, 0x3f803f80u, 0x3f803f80u};
    const bf16x8 ones = onesu.b;

    // V staging indices: one key-pair x 8-d chunk per thread
    const int vkp = tid & 31, vdg = tid >> 5;

#pragma unroll
    for (int tile = 0; tile < 2; tile++) {
        const int qt = tile == 0 ? qx : 31 - qx;
        const int qrow0 = qt * 64 + wid * 16;

        bf16x8 qf[2];
        {
            const u16* qp = qbase + (size_t)(qrow0 + am) * 3072 + grp * 8;
            qf[0] = *(const bf16x8*)(qp);
            qf[1] = *(const bf16x8*)(qp + 32);
        }

        f32x4 O[4], Ol;
        float m_i[4];
#pragma unroll
        for (int j = 0; j < 4; j++) O[j] = (f32x4){0.f, 0.f, 0.f, 0.f};
        Ol = (f32x4){0.f, 0.f, 0.f, 0.f};
#pragma unroll
        for (int r = 0; r < 4; r++) m_i[r] = -1e30f;

        const int ktend = qt * 64;
        for (int kt = 0; kt <= ktend; kt += 64) {
            __syncthreads();
            // ---- stage K: 2 chunks/thread, [64][72] u16
#pragma unroll
            for (int cc = 0; cc < 2; cc++) {
                const int c = tid + cc * 256;
                const int row = c >> 3, c8 = (c & 7) * 8;
                *(uint4*)(&Ks[row * 72 + c8]) =
                    *(const uint4*)(kbase + (size_t)(kt + row) * 3072 + c8);
            }
            // ---- stage V transposed as key-pair u32s: Vt32[d][kp]
            {
                const u16* v0 = vbase + (size_t)(kt + 2 * vkp) * 3072 + vdg * 8;
                uint4 lo = *(const uint4*)(v0);
                uint4 hi = *(const uint4*)(v0 + 3072);
                const u16* lp = (const u16*)&lo;
                const u16* hp = (const u16*)&hi;
#pragma unroll
                for (int j = 0; j < 8; j++)
                    Vt32[(vdg * 8 + j) * 33 + vkp] =
                        (uint)lp[j] | ((uint)hp[j] << 16);
            }
            __syncthreads();

            // ---- QK^T: S[16q][64k], 4 kk-slices
            f32x4 st[4];
#pragma unroll
            for (int kk = 0; kk < 4; kk++) {
                const u16* kb = &Ks[(kk * 16 + am) * 72 + grp * 8];
                bf16x8 k0 = *(const bf16x8*)(kb);
                bf16x8 k1 = *(const bf16x8*)(kb + 32);
                f32x4 s = (f32x4){0.f, 0.f, 0.f, 0.f};
                s = __builtin_amdgcn_mfma_f32_16x16x32_bf16(qf[0], k0, s, 0, 0, 0);
                s = __builtin_amdgcn_mfma_f32_16x16x32_bf16(qf[1], k1, s, 0, 0, 0);
                st[kk] = s;
            }
            // ---- causal mask (diagonal tile only; wave-uniform branch)
            if (kt == ktend) {
#pragma unroll
                for (int kk = 0; kk < 4; kk++) {
                    const int kg = kt + kk * 16 + am;
#pragma unroll
                    for (int r = 0; r < 4; r++) {
                        const int qg = qrow0 + grp * 4 + r;
                        if (kg > qg) st[kk][r] = -1e30f;
                    }
                }
            }
            // ---- online softmax: max (local + 16-lane shuffle), exp
            float mx[4], alpha[4];
#pragma unroll
            for (int r = 0; r < 4; r++)
                mx[r] = fmaxf(fmaxf(st[0][r], st[1][r]),
                              fmaxf(st[2][r], st[3][r]));
#pragma unroll
            for (int o = 1; o < 16; o <<= 1)
#pragma unroll
                for (int r = 0; r < 4; r++)
                    mx[r] = fmaxf(mx[r], __shfl_xor(mx[r], o));
#pragma unroll
            for (int r = 0; r < 4; r++) {
                const float mnew = fmaxf(m_i[r], mx[r]);
                alpha[r] = __expf(m_i[r] - mnew);
                m_i[r] = mnew;
            }
#pragma unroll
            for (int kk = 0; kk < 4; kk++)
#pragma unroll
                for (int r = 0; r < 4; r++)
                    st[kk][r] = __expf(st[kk][r] - m_i[r]);
#pragma unroll
            for (int j = 0; j < 4; j++)
#pragma unroll
                for (int r = 0; r < 4; r++) O[j][r] *= alpha[r];
#pragma unroll
            for (int r = 0; r < 4; r++) Ol[r] *= alpha[r];

            // ---- P: C-layout -> per-wave LDS -> A-layout
            u16* pw = &Ps[wid][0];
#pragma unroll
            for (int kk = 0; kk < 4; kk++)
#pragma unroll
                for (int r = 0; r < 4; r++)
                    pw[(grp * 4 + r) * 72 + kk * 16 + am] = f2b(st[kk][r]);
            asm volatile("s_waitcnt lgkmcnt(0)" ::: "memory");

            // ---- PV + ones-column l accumulation
#pragma unroll
            for (int hh = 0; hh < 2; hh++) {
                bf16x8 pf = *(const bf16x8*)(&pw[am * 72 + hh * 32 + grp * 8]);
                Ol = __builtin_amdgcn_mfma_f32_16x16x32_bf16(pf, ones, Ol, 0, 0, 0);
#pragma unroll
                for (int jt = 0; jt < 4; jt++) {
                    const int d = jt * 16 + am;
                    const uint* vp = &Vt32[d * 33 + hh * 16 + grp * 4];
                    union { uint4 u; bf16x8 b; } vv;
                    vv.u = (uint4){vp[0], vp[1], vp[2], vp[3]};
                    O[jt] = __builtin_amdgcn_mfma_f32_16x16x32_bf16(
                        pf, vv.b, O[jt], 0, 0, 0);
                }
            }
        }

        // ---- epilogue for this q-tile
        u16* aorow = ao + (tok0 + qrow0) * 1024 + h * 64;
#pragma unroll
        for (int r = 0; r < 4; r++) {
            const int q = grp * 4 + r;
            const float invl = 1.f / Ol[r];
#pragma unroll
            for (int jt = 0; jt < 4; jt++)
                aorow[(size_t)q * 1024 + jt * 16 + am] = f2b(O[jt][r] * invl);
        }
    }
}

// ---------------------------------------------------------------------------
extern "C" void kernel_launch(void* const* d_in, const int* in_sizes, int n_in,
                              void* d_out, int out_size, void* d_ws, size_t ws_size,
                              hipStream_t stream)
{
    (void)in_sizes; (void)n_in; (void)out_size; (void)ws_size;
    const float* x     = (const float*)d_in[0];
    const float* wq    = (const float*)d_in[1];
    const float* wk    = (const float*)d_in[2];
    const float* wv    = (const float*)d_in[3];
    const float* wo    = (const float*)d_in[4];
    const float* ln1   = (const float*)d_in[5];
    const float* ln2   = (const float*)d_in[6];
    const float* wup   = (const float*)d_in[7];
    const float* wgate = (const float*)d_in[8];
    const float* wdown = (const float*)d_in[9];
    float* out = (float*)d_out;
    char* ws = (char*)d_ws;
    const size_t MB = 1024 * 1024;

    u16*   xn   = (u16*)(ws);
    u16*   ao   = (u16*)(ws);
    u16*   qkv  = (u16*)(ws + 16 * MB);
    u16*   hbuf = (u16*)(ws + 16 * MB);
    float* x1   = (float*)(ws + 80 * MB);
    u16*   bwq  = (u16*)(ws + 112 * MB);             // [wq|wk|wv] contiguous
    u16*   bwk  = (u16*)(ws + 114 * MB);
    u16*   bwv  = (u16*)(ws + 116 * MB);
    u16*   bwo  = (u16*)(ws + 118 * MB);
    u16*   bwup = (u16*)(ws + 120 * MB);
    u16*   bwgt = (u16*)(ws + 128 * MB);
    u16*   bwdn = (u16*)(ws + 136 * MB);
    float* cst  = (float*)(ws + 144 * MB);
    float* snt  = (float*)(ws + 144 * MB + 262144);

    const int n4_1m = (1024 * 1024) / 4;
    const int n4_4m = (4096 * 1024) / 4;
    cvt_bf16<<<(n4_1m + 255) / 256, 256, 0, stream>>>(wq,    bwq,  n4_1m);
    cvt_bf16<<<(n4_1m + 255) / 256, 256, 0, stream>>>(wk,    bwk,  n4_1m);
    cvt_bf16<<<(n4_1m + 255) / 256, 256, 0, stream>>>(wv,    bwv,  n4_1m);
    cvt_bf16<<<(n4_1m + 255) / 256, 256, 0, stream>>>(wo,    bwo,  n4_1m);
    cvt_bf16<<<(n4_4m + 255) / 256, 256, 0, stream>>>(wup,   bwup, n4_4m);
    cvt_bf16<<<(n4_4m + 255) / 256, 256, 0, stream>>>(wgate, bwgt, n4_4m);
    cvt_bf16<<<(n4_4m + 255) / 256, 256, 0, stream>>>(wdown, bwdn, n4_4m);

    rope_tab<<<SEQ, 32, 0, stream>>>(cst, snt);
    rmsnorm_k<<<NTOK, 256, 0, stream>>>(x, ln1, xn);
    // fused QKV: B = [wq|wk|wv] (3072 rows), C = qkv[8192][3072]
    gemm_bt<0><<<dim3(24, 64), 256, 0, stream>>>(xn, bwq, qkv, nullptr, NTOK, 3072, 1024, 3072, 0);
    rope_apply<<<NTOK, 256, 0, stream>>>(qkv, cst, snt);
    attn<<<dim3(64, 16), 256, 0, stream>>>(qkv, ao);
    gemm_bt<1><<<dim3(8, 64), 256, 0, stream>>>(ao, bwo, x1, x, NTOK, 1024, 1024, 1024, 0);
    rmsnorm_k<<<NTOK, 256, 0, stream>>>(x1, ln2, xn);
    gemm_bt<0><<<dim3(32, 64), 256, 0, stream>>>(xn, bwgt, hbuf, nullptr, NTOK, 4096, 1024, 4096, 0);
    gemm_bt<2><<<dim3(32, 64), 256, 0, stream>>>(xn, bwup, hbuf, hbuf, NTOK, 4096, 1024, 4096, 0);
    gemm_bt<1><<<dim3(8, 64), 256, 0, stream>>>(hbuf, bwdn, out, x1, NTOK, 1024, 4096, 1024, 0);
}